// Round 3
// baseline (797.764 us; speedup 1.0000x reference)
//
#include <hip/hip_runtime.h>

#define N_NODES 100000
#define N_EDGES 3200000
#define NB ((N_NODES + 255) / 256)   // 391 blocks over nodes
#define NBUCKET NB                   // coarse buckets = dst>>8 -> 391
#define CAP2 1664                    // per (bucket, xcd-slice) capacity; mean 1024, sigma 32
#define LBUF 10368                   // staging for one bucket (mean 8192, sigma ~90)

// ---------------- pass 1: fused degree count + coarse partition ----------------
// part item layout: bits[16:0] = src, bits[24:17] = dst & 255

__global__ void k_init(int* __restrict__ bcur8) {
  int i = blockIdx.x * blockDim.x + threadIdx.x;
  if (i < NBUCKET * 8) bcur8[i] = i * CAP2;
}

__global__ void k_pass1(const int* __restrict__ src, const int* __restrict__ dst,
                        int* __restrict__ deg, int* __restrict__ bcur8,
                        unsigned int* __restrict__ part) {
  int e = blockIdx.x * blockDim.x + threadIdx.x;
  if (e >= N_EDGES) return;
  int d = dst[e];
  int s = src[e];
  atomicAdd(&deg[d], 1);
  int sub = (d >> 8) * 8 + (blockIdx.x & 7);   // XCD-sliced sub-region
  int p = atomicAdd(&bcur8[sub], 1);
  if (p < (sub + 1) * CAP2)                    // overflow guard (6.5 sigma)
    part[p] = (unsigned)s | ((unsigned)(d & 255) << 17);
}

// ---------------- scans: deg -> rs (exclusive), dis = rsqrt(deg+1) ----------------

__global__ void k_scan1(const int* __restrict__ deg, int* __restrict__ rs,
                        float* __restrict__ dis, int* __restrict__ blksums) {
  __shared__ int sh[256];
  int tid = threadIdx.x;
  int i = blockIdx.x * 256 + tid;
  int v = (i < N_NODES) ? deg[i] : 0;
  if (i < N_NODES) dis[i] = rsqrtf((float)(v + 1));
  int x = v;
  sh[tid] = x;
  __syncthreads();
  for (int off = 1; off < 256; off <<= 1) {
    int t = (tid >= off) ? sh[tid - off] : 0;
    __syncthreads();
    x += t;
    sh[tid] = x;
    __syncthreads();
  }
  if (i < N_NODES) rs[i] = x - v;
  if (tid == 255) blksums[blockIdx.x] = x;
}

__global__ void k_scan2(int* blksums) {
  __shared__ int sh[512];
  int tid = threadIdx.x;
  int v = (tid < NB) ? blksums[tid] : 0;
  int x = v;
  sh[tid] = x;
  __syncthreads();
  for (int off = 1; off < 512; off <<= 1) {
    int t = (tid >= off) ? sh[tid - off] : 0;
    __syncthreads();
    x += t;
    sh[tid] = x;
    __syncthreads();
  }
  if (tid < NB) blksums[tid] = x - v;
}

__global__ void k_scan3(int* __restrict__ rs, const int* __restrict__ blksums) {
  int i = blockIdx.x * 256 + threadIdx.x;
  if (i < N_NODES) rs[i] += blksums[blockIdx.x];
  if (i == 0) rs[N_NODES] = N_EDGES;
}

// ---------------- pass 2: in-bucket counting sort via LDS, coalesced csr write ----
// Bucket b holds nodes [b*256, b*256+256); bucket start == rs[b*256] by construction.
// Per-node offsets come free from rs — no histogram needed.

__global__ void __launch_bounds__(256) k_part2(const unsigned int* __restrict__ part,
                                               const int* __restrict__ bcur8,
                                               const int* __restrict__ rs,
                                               int* __restrict__ csr) {
  __shared__ unsigned int cur[256];
  __shared__ unsigned int buf[LBUF];
  int b = blockIdx.x;
  int n0 = b << 8;
  int base = rs[n0];
  int nend = min(n0 + 256, N_NODES);
  int total = rs[nend] - base;
  int tid = threadIdx.x;
  int node = n0 + tid;
  cur[tid] = (node < nend) ? (unsigned)(rs[node] - base) : 0u;
  __syncthreads();
  bool stage = (total <= LBUF);
  for (int r = 0; r < 8; ++r) {
    int sub = b * 8 + r;
    int start = sub * CAP2;
    int len = min(bcur8[sub] - start, CAP2);
    for (int i = tid; i < len; i += 256) {
      unsigned v = part[start + i];
      unsigned low = v >> 17;
      unsigned s = v & 0x1FFFFu;
      unsigned lpos = atomicAdd(&cur[low], 1u);
      if (stage) buf[lpos] = s;
      else       csr[base + (int)lpos] = (int)s;
    }
  }
  __syncthreads();
  if (stage)
    for (int i = tid; i < total; i += 256) csr[base + i] = (int)buf[i];
}

// ---------------- Layer 1: aggregate x (4 feats) then transform ----------------

__global__ void k_agg1(const float4* __restrict__ x4, const float* __restrict__ dis,
                       const int* __restrict__ rs, const int* __restrict__ csr,
                       float4* __restrict__ agg1) {
  int n = blockIdx.x * blockDim.x + threadIdx.x;
  if (n >= N_NODES) return;
  float dn = dis[n];
  float4 xv = x4[n];
  float ax = xv.x * dn, ay = xv.y * dn, az = xv.z * dn, aw = xv.w * dn;
  int e1 = rs[n + 1];
  for (int e = rs[n]; e < e1; ++e) {
    int s = csr[e];
    float ds_ = dis[s];
    float4 xs = x4[s];
    ax += xs.x * ds_; ay += xs.y * ds_; az += xs.z * ds_; aw += xs.w * ds_;
  }
  float4 r; r.x = ax * dn; r.y = ay * dn; r.z = az * dn; r.w = aw * dn;
  agg1[n] = r;
}

__global__ void k_xform1(const float4* __restrict__ agg1, const float* __restrict__ W1,
                         const float* __restrict__ b1, float* __restrict__ h1) {
  int t = blockIdx.x * blockDim.x + threadIdx.x;
  if (t >= N_NODES * 64) return;
  int n = t >> 6, j = t & 63;
  float4 a = agg1[n];
  float s = b1[j] + a.x * W1[j] + a.y * W1[64 + j] + a.z * W1[128 + j] + a.w * W1[192 + j];
  h1[t] = fmaxf(s, 0.0f);
}

// ---------------- Layer 2 fused: aggregate h1, W2+b2+relu, Wf+bf head ----------------

__global__ void __launch_bounds__(256)
k_layer2(const float* __restrict__ h1, const float* __restrict__ dis,
         const int* __restrict__ rs, const int* __restrict__ csr,
         const float* __restrict__ W2, const float* __restrict__ b2,
         const float* __restrict__ Wf, const float* __restrict__ bf,
         float* __restrict__ out) {
  __shared__ float sh[4][64];
  int lane = threadIdx.x & 63;
  int w = threadIdx.x >> 6;
  int n = blockIdx.x * 4 + w;   // grid = N/4 exactly

  float dn = dis[n];
  float acc = h1[n * 64 + lane] * dn;   // self-loop term
  int e = rs[n], e1 = rs[n + 1];
  for (; e + 1 < e1; e += 2) {
    int s0 = csr[e], s1 = csr[e + 1];
    float d0 = dis[s0], d1 = dis[s1];
    float v0 = h1[s0 * 64 + lane];
    float v1 = h1[s1 * 64 + lane];
    acc += v0 * d0;
    acc += v1 * d1;
  }
  if (e < e1) {
    int s = csr[e];
    acc += h1[s * 64 + lane] * dis[s];
  }
  acc *= dn;

  sh[w][lane] = acc;
  __syncthreads();

  float t = b2[lane];
#pragma unroll 16
  for (int j = 0; j < 64; ++j) t += sh[w][j] * W2[j * 64 + lane];
  t = fmaxf(t, 0.0f);

  float p0 = t * Wf[lane * 2 + 0];
  float p1 = t * Wf[lane * 2 + 1];
  for (int off = 32; off; off >>= 1) {
    p0 += __shfl_down(p0, off);
    p1 += __shfl_down(p1, off);
  }
  if (lane == 0) {
    out[n * 2 + 0] = p0 + bf[0];
    out[n * 2 + 1] = p1 + bf[1];
  }
}

// ---------------- launch ----------------

extern "C" void kernel_launch(void* const* d_in, const int* in_sizes, int n_in,
                              void* d_out, int out_size, void* d_ws, size_t ws_size,
                              hipStream_t stream) {
  const float* x  = (const float*)d_in[0];
  const int*   ei = (const int*)d_in[1];     // [2, E] row-major, int32
  const float* W1 = (const float*)d_in[2];
  const float* b1 = (const float*)d_in[3];
  const float* W2 = (const float*)d_in[4];
  const float* b2 = (const float*)d_in[5];
  const float* Wf = (const float*)d_in[6];
  const float* bf = (const float*)d_in[7];
  float* out = (float*)d_out;

  const int* srcv = ei;
  const int* dstv = ei + N_EDGES;

  // workspace carve-up (256B aligned). part[] overlays h1 (time-disjoint).
  char* p = (char*)d_ws;
  auto take = [&](size_t bytes) { char* r = p; p += (bytes + 255) & ~(size_t)255; return r; };
  int*   deg     = (int*)take((size_t)N_NODES * 4);
  int*   rs      = (int*)take((size_t)(N_NODES + 1) * 4);
  int*   bcur8   = (int*)take((size_t)NBUCKET * 8 * 4);
  int*   csr     = (int*)take((size_t)N_EDGES * 4);
  float* dis     = (float*)take((size_t)N_NODES * 4);
  float* agg1    = (float*)take((size_t)N_NODES * 16);
  int*   blksums = (int*)take(512 * 4);
  // overlay region: max(part = NBUCKET*8*CAP2*4 ≈ 20.8 MB, h1 = 25.6 MB)
  char*  ov      = take((size_t)N_NODES * 64 * 4);
  unsigned int* part = (unsigned int*)ov;
  float*        h1   = (float*)ov;

  (void)hipMemsetAsync(deg, 0, (size_t)N_NODES * 4, stream);
  k_init <<<(NBUCKET * 8 + 255) / 256, 256, 0, stream>>>(bcur8);
  k_pass1<<<(N_EDGES + 255) / 256, 256, 0, stream>>>(srcv, dstv, deg, bcur8, part);
  k_scan1<<<NB, 256, 0, stream>>>(deg, rs, dis, blksums);
  k_scan2<<<1, 512, 0, stream>>>(blksums);
  k_scan3<<<NB, 256, 0, stream>>>(rs, blksums);
  k_part2<<<NBUCKET, 256, 0, stream>>>(part, bcur8, rs, csr);
  k_agg1 <<<NB, 256, 0, stream>>>((const float4*)x, dis, rs, csr, (float4*)agg1);
  k_xform1<<<(N_NODES * 64 + 255) / 256, 256, 0, stream>>>((const float4*)agg1, W1, b1, h1);
  k_layer2<<<N_NODES / 4, 256, 0, stream>>>(h1, dis, rs, csr, W2, b2, Wf, bf, out);
}

// Round 4
// 341.730 us; speedup vs baseline: 2.3345x; 2.3345x over previous
//
#include <hip/hip_runtime.h>

#define N_NODES 100000
#define N_EDGES 3200000
#define NB ((N_NODES + 255) / 256)   // 391
#define NBUCKET NB                   // coarse bucket = dst>>8
#define EPB 8192                     // edges per k_pass1 block
#define NPB ((N_EDGES + EPB - 1) / EPB)  // 391 blocks
#define BCAP 8704                    // per-bucket capacity; mean 8192, sigma 90 (5.7σ)

// ---------------- pass 1: LDS-staged coarse partition ----------------
// item: bits[16:0] = src, bits[24:17] = dst & 255. bucket = dst>>8.

__global__ void __launch_bounds__(256) k_pass1(const int* __restrict__ src,
                                               const int* __restrict__ dst,
                                               int* __restrict__ gcur,
                                               unsigned int* __restrict__ eb) {
  __shared__ unsigned int sdata[EPB];
  __shared__ unsigned short sbid[EPB];
  __shared__ int hist[NBUCKET], cur[NBUCKET], gbase[NBUCKET];
  int tid = threadIdx.x;
  int base = blockIdx.x * EPB;
  int cnt = min(EPB, N_EDGES - base);
  for (int i = tid; i < NBUCKET; i += 256) { hist[i] = 0; cur[i] = 0; }
  __syncthreads();
  for (int i = tid; i < cnt; i += 256) {
    int e = base + i;
    int d = dst[e], s = src[e];
    int b = d >> 8;
    sdata[i] = (unsigned)s | ((unsigned)(d & 255) << 17);
    sbid[i] = (unsigned short)b;
    atomicAdd(&hist[b], 1);
  }
  __syncthreads();
  for (int b = tid; b < NBUCKET; b += 256) {
    int h = hist[b];
    if (h) gbase[b] = atomicAdd(&gcur[b], h);   // one claim per (block,bucket)
  }
  __syncthreads();
  // write each bucket's run into its claimed contiguous window (line-friendly)
  for (int i = tid; i < cnt; i += 256) {
    int b = sbid[i];
    int pos = gbase[b] + atomicAdd(&cur[b], 1);
    if (pos < BCAP) eb[b * BCAP + pos] = sdata[i];
  }
}

// ---------------- pass 2: per-bucket counting sort, node meta ----------------
// Bucket b owns nodes [b*256, b*256+256). In-place: eb run becomes csr run.

__global__ void __launch_bounds__(256) k_part2(unsigned int* __restrict__ eb,
                                               const int* __restrict__ gcur,
                                               int* __restrict__ rs, int* __restrict__ re,
                                               float* __restrict__ dis) {
  __shared__ int hist[256], scn[256], cur[256];
  __shared__ unsigned int stage[BCAP];
  int b = blockIdx.x, tid = threadIdx.x;
  int n0 = b << 8;
  int cnt = min(gcur[b], BCAP);
  int base = b * BCAP;
  hist[tid] = 0; cur[tid] = 0;
  __syncthreads();
  for (int i = tid; i < cnt; i += 256)
    atomicAdd(&hist[eb[base + i] >> 17], 1);
  __syncthreads();
  int deg = hist[tid];
  int x = deg;
  scn[tid] = x;
  __syncthreads();
  for (int off = 1; off < 256; off <<= 1) {
    int t = (tid >= off) ? scn[tid - off] : 0;
    __syncthreads();
    x += t; scn[tid] = x;
    __syncthreads();
  }
  int excl = x - deg;
  int n = n0 + tid;
  if (n < N_NODES) {
    rs[n]  = base + excl;
    re[n]  = base + excl + deg;
    dis[n] = rsqrtf((float)(deg + 1));
  }
  scn[tid] = excl;
  __syncthreads();
  for (int i = tid; i < cnt; i += 256) {
    unsigned v = eb[base + i];
    int lpos = scn[v >> 17] + atomicAdd(&cur[v >> 17], 1);
    stage[lpos] = v & 0x1FFFFu;
  }
  __syncthreads();
  for (int i = tid; i < cnt; i += 256)
    eb[base + i] = stage[i];     // eb is now csr (src ids, grouped by dst node)
}

// ---------------- Layer 1: aggregate x (4 feats) then transform ----------------

__global__ void k_agg1(const float4* __restrict__ x4, const float* __restrict__ dis,
                       const int* __restrict__ rs, const int* __restrict__ re,
                       const int* __restrict__ csr, float4* __restrict__ agg1) {
  int n = blockIdx.x * blockDim.x + threadIdx.x;
  if (n >= N_NODES) return;
  float dn = dis[n];
  float4 xv = x4[n];
  float ax = xv.x * dn, ay = xv.y * dn, az = xv.z * dn, aw = xv.w * dn;
  int e1 = re[n];
  for (int e = rs[n]; e < e1; ++e) {
    int s = csr[e];
    float ds_ = dis[s];
    float4 xs = x4[s];
    ax += xs.x * ds_; ay += xs.y * ds_; az += xs.z * ds_; aw += xs.w * ds_;
  }
  float4 r; r.x = ax * dn; r.y = ay * dn; r.z = az * dn; r.w = aw * dn;
  agg1[n] = r;
}

// h1s[n][j] = relu(b1[j] + agg1[n]·W1[:,j]) * dis[n]   (dis folded in!)
__global__ void k_xform1(const float4* __restrict__ agg1, const float* __restrict__ W1,
                         const float* __restrict__ b1, const float* __restrict__ dis,
                         float* __restrict__ h1s) {
  int t = blockIdx.x * blockDim.x + threadIdx.x;
  if (t >= N_NODES * 64) return;
  int n = t >> 6, j = t & 63;
  float4 a = agg1[n];
  float s = b1[j] + a.x * W1[j] + a.y * W1[64 + j] + a.z * W1[128 + j] + a.w * W1[192 + j];
  h1s[t] = fmaxf(s, 0.0f) * dis[n];
}

// ---------------- Layer 2 fused: gather h1s, W2+b2+relu, Wf+bf head ----------------

__global__ void __launch_bounds__(256)
k_layer2(const float* __restrict__ h1s, const float* __restrict__ dis,
         const int* __restrict__ rs, const int* __restrict__ re,
         const int* __restrict__ csr,
         const float* __restrict__ W2, const float* __restrict__ b2,
         const float* __restrict__ Wf, const float* __restrict__ bf,
         float* __restrict__ out) {
  __shared__ float sh[4][64];
  int lane = threadIdx.x & 63;
  int w = threadIdx.x >> 6;
  int n = blockIdx.x * 4 + w;   // grid = N/4 exactly

  float dn = dis[n];
  float acc0 = h1s[n * 64 + lane];   // self-loop: h1[n]*dn already folded
  float acc1 = 0.0f;
  int e = rs[n], e1 = re[n];
  for (; e + 3 < e1; e += 4) {
    int s0 = csr[e], s1 = csr[e + 1], s2 = csr[e + 2], s3 = csr[e + 3];
    float v0 = h1s[s0 * 64 + lane];
    float v1 = h1s[s1 * 64 + lane];
    float v2 = h1s[s2 * 64 + lane];
    float v3 = h1s[s3 * 64 + lane];
    acc0 += v0 + v2;
    acc1 += v1 + v3;
  }
  for (; e < e1; ++e) acc1 += h1s[csr[e] * 64 + lane];
  float acc = (acc0 + acc1) * dn;

  sh[w][lane] = acc;
  __syncthreads();

  float t = b2[lane];
#pragma unroll 16
  for (int j = 0; j < 64; ++j) t += sh[w][j] * W2[j * 64 + lane];
  t = fmaxf(t, 0.0f);

  float p0 = t * Wf[lane * 2 + 0];
  float p1 = t * Wf[lane * 2 + 1];
  for (int off = 32; off; off >>= 1) {
    p0 += __shfl_down(p0, off);
    p1 += __shfl_down(p1, off);
  }
  if (lane == 0) {
    out[n * 2 + 0] = p0 + bf[0];
    out[n * 2 + 1] = p1 + bf[1];
  }
}

// ---------------- launch ----------------

extern "C" void kernel_launch(void* const* d_in, const int* in_sizes, int n_in,
                              void* d_out, int out_size, void* d_ws, size_t ws_size,
                              hipStream_t stream) {
  const float* x  = (const float*)d_in[0];
  const int*   ei = (const int*)d_in[1];     // [2, E] row-major, int32
  const float* W1 = (const float*)d_in[2];
  const float* b1 = (const float*)d_in[3];
  const float* W2 = (const float*)d_in[4];
  const float* b2 = (const float*)d_in[5];
  const float* Wf = (const float*)d_in[6];
  const float* bf = (const float*)d_in[7];
  float* out = (float*)d_out;

  const int* srcv = ei;
  const int* dstv = ei + N_EDGES;

  // workspace carve-up (256B aligned), ~42 MB
  char* p = (char*)d_ws;
  auto take = [&](size_t bytes) { char* r = p; p += (bytes + 255) & ~(size_t)255; return r; };
  int*          gcur = (int*)take((size_t)NBUCKET * 4);
  unsigned int* eb   = (unsigned int*)take((size_t)NBUCKET * BCAP * 4);  // 13.6 MB, becomes csr
  int*          rs   = (int*)take((size_t)N_NODES * 4);
  int*          re   = (int*)take((size_t)N_NODES * 4);
  float*        dis  = (float*)take((size_t)N_NODES * 4);
  float*        agg1 = (float*)take((size_t)N_NODES * 16);
  float*        h1s  = (float*)take((size_t)N_NODES * 64 * 4);            // 25.6 MB

  (void)hipMemsetAsync(gcur, 0, (size_t)NBUCKET * 4, stream);
  k_pass1<<<NPB, 256, 0, stream>>>(srcv, dstv, gcur, eb);
  k_part2<<<NBUCKET, 256, 0, stream>>>(eb, gcur, rs, re, dis);
  const int* csr = (const int*)eb;
  k_agg1 <<<NB, 256, 0, stream>>>((const float4*)x, dis, rs, re, csr, (float4*)agg1);
  k_xform1<<<(N_NODES * 64 + 255) / 256, 256, 0, stream>>>((const float4*)agg1, W1, b1, dis, h1s);
  k_layer2<<<N_NODES / 4, 256, 0, stream>>>(h1s, dis, rs, re, csr, W2, b2, Wf, bf, out);
}

// Round 5
// 321.756 us; speedup vs baseline: 2.4794x; 1.0621x over previous
//
#include <hip/hip_runtime.h>
#include <hip/hip_bf16.h>

#define N_NODES 100000
#define N_EDGES 3200000
#define NB ((N_NODES + 255) / 256)   // 391
#define NBUCKET NB                   // coarse bucket = dst>>8
#define EPB 8192                     // edges per k_pass1 block
#define NPB ((N_EDGES + EPB - 1) / EPB)  // 391 blocks
#define BCAP 8704                    // per-bucket capacity; mean 8192, sigma 90 (5.7σ)

// ---------------- pass 1: LDS-staged coarse partition ----------------
// item: bits[16:0] = src, bits[24:17] = dst & 255. bucket = dst>>8.

__global__ void __launch_bounds__(256) k_pass1(const int* __restrict__ src,
                                               const int* __restrict__ dst,
                                               int* __restrict__ gcur,
                                               unsigned int* __restrict__ eb) {
  __shared__ unsigned int sdata[EPB];
  __shared__ unsigned short sbid[EPB];
  __shared__ int hist[NBUCKET], cur[NBUCKET], gbase[NBUCKET];
  int tid = threadIdx.x;
  int base = blockIdx.x * EPB;
  int cnt = min(EPB, N_EDGES - base);
  for (int i = tid; i < NBUCKET; i += 256) { hist[i] = 0; cur[i] = 0; }
  __syncthreads();
  for (int i = tid; i < cnt; i += 256) {
    int e = base + i;
    int d = dst[e], s = src[e];
    int b = d >> 8;
    sdata[i] = (unsigned)s | ((unsigned)(d & 255) << 17);
    sbid[i] = (unsigned short)b;
    atomicAdd(&hist[b], 1);
  }
  __syncthreads();
  for (int b = tid; b < NBUCKET; b += 256) {
    int h = hist[b];
    if (h) gbase[b] = atomicAdd(&gcur[b], h);   // one claim per (block,bucket)
  }
  __syncthreads();
  for (int i = tid; i < cnt; i += 256) {
    int b = sbid[i];
    int pos = gbase[b] + atomicAdd(&cur[b], 1);
    if (pos < BCAP) eb[b * BCAP + pos] = sdata[i];
  }
}

// ---------------- pass 2: per-bucket counting sort, node meta ----------------

__global__ void __launch_bounds__(256) k_part2(unsigned int* __restrict__ eb,
                                               const int* __restrict__ gcur,
                                               int* __restrict__ rs, int* __restrict__ re,
                                               float* __restrict__ dis) {
  __shared__ int hist[256], scn[256], cur[256];
  __shared__ unsigned int stage[BCAP];
  int b = blockIdx.x, tid = threadIdx.x;
  int n0 = b << 8;
  int cnt = min(gcur[b], BCAP);
  int base = b * BCAP;
  hist[tid] = 0; cur[tid] = 0;
  __syncthreads();
  for (int i = tid; i < cnt; i += 256)
    atomicAdd(&hist[eb[base + i] >> 17], 1);
  __syncthreads();
  int deg = hist[tid];
  int x = deg;
  scn[tid] = x;
  __syncthreads();
  for (int off = 1; off < 256; off <<= 1) {
    int t = (tid >= off) ? scn[tid - off] : 0;
    __syncthreads();
    x += t; scn[tid] = x;
    __syncthreads();
  }
  int excl = x - deg;
  int n = n0 + tid;
  if (n < N_NODES) {
    rs[n]  = base + excl;
    re[n]  = base + excl + deg;
    dis[n] = rsqrtf((float)(deg + 1));
  }
  scn[tid] = excl;
  __syncthreads();
  for (int i = tid; i < cnt; i += 256) {
    unsigned v = eb[base + i];
    int lpos = scn[v >> 17] + atomicAdd(&cur[v >> 17], 1);
    stage[lpos] = v & 0x1FFFFu;
  }
  __syncthreads();
  for (int i = tid; i < cnt; i += 256)
    eb[base + i] = stage[i];     // eb is now csr (src ids, grouped by dst node)
}

// ---------------- Layer 1: aggregate x (4 feats) then transform ----------------

__global__ void k_agg1(const float4* __restrict__ x4, const float* __restrict__ dis,
                       const int* __restrict__ rs, const int* __restrict__ re,
                       const int* __restrict__ csr, float4* __restrict__ agg1) {
  int n = blockIdx.x * blockDim.x + threadIdx.x;
  if (n >= N_NODES) return;
  float dn = dis[n];
  float4 xv = x4[n];
  float ax = xv.x * dn, ay = xv.y * dn, az = xv.z * dn, aw = xv.w * dn;
  int e1 = re[n];
  for (int e = rs[n]; e < e1; ++e) {
    int s = csr[e];
    float ds_ = dis[s];
    float4 xs = x4[s];
    ax += xs.x * ds_; ay += xs.y * ds_; az += xs.z * ds_; aw += xs.w * ds_;
  }
  float4 r; r.x = ax * dn; r.y = ay * dn; r.z = az * dn; r.w = aw * dn;
  agg1[n] = r;
}

// h1s[n][j] = bf16( relu(b1[j] + agg1[n]·W1[:,j]) * dis[n] )
__global__ void k_xform1(const float4* __restrict__ agg1, const float* __restrict__ W1,
                         const float* __restrict__ b1, const float* __restrict__ dis,
                         __hip_bfloat16* __restrict__ h1s) {
  int t = blockIdx.x * blockDim.x + threadIdx.x;
  if (t >= N_NODES * 64) return;
  int n = t >> 6, j = t & 63;
  float4 a = agg1[n];
  float s = b1[j] + a.x * W1[j] + a.y * W1[64 + j] + a.z * W1[128 + j] + a.w * W1[192 + j];
  h1s[t] = __float2bfloat16(fmaxf(s, 0.0f) * dis[n]);
}

// ---------------- Layer 2 fused: gather bf16 h1s, W2+b2+relu, Wf+bf head ----------

__global__ void __launch_bounds__(256)
k_layer2(const __hip_bfloat16* __restrict__ h1s, const float* __restrict__ dis,
         const int* __restrict__ rs, const int* __restrict__ re,
         const int* __restrict__ csr,
         const float* __restrict__ W2, const float* __restrict__ b2,
         const float* __restrict__ Wf, const float* __restrict__ bf,
         float* __restrict__ out) {
  __shared__ float sh[4][64];
  int lane = threadIdx.x & 63;
  int w = threadIdx.x >> 6;
  int n = blockIdx.x * 4 + w;   // grid = N/4 exactly

  float dn = dis[n];
  float acc0 = __bfloat162float(h1s[n * 64 + lane]);   // self-loop (dis folded)
  float acc1 = 0.0f, acc2 = 0.0f, acc3 = 0.0f;
  int e = rs[n], e1 = re[n];
  for (; e + 7 < e1; e += 8) {
    int s0 = csr[e],     s1 = csr[e + 1], s2 = csr[e + 2], s3 = csr[e + 3];
    int s4 = csr[e + 4], s5 = csr[e + 5], s6 = csr[e + 6], s7 = csr[e + 7];
    float v0 = __bfloat162float(h1s[s0 * 64 + lane]);
    float v1 = __bfloat162float(h1s[s1 * 64 + lane]);
    float v2 = __bfloat162float(h1s[s2 * 64 + lane]);
    float v3 = __bfloat162float(h1s[s3 * 64 + lane]);
    float v4 = __bfloat162float(h1s[s4 * 64 + lane]);
    float v5 = __bfloat162float(h1s[s5 * 64 + lane]);
    float v6 = __bfloat162float(h1s[s6 * 64 + lane]);
    float v7 = __bfloat162float(h1s[s7 * 64 + lane]);
    acc0 += v0 + v4;
    acc1 += v1 + v5;
    acc2 += v2 + v6;
    acc3 += v3 + v7;
  }
  for (; e < e1; ++e) acc1 += __bfloat162float(h1s[csr[e] * 64 + lane]);
  float acc = ((acc0 + acc1) + (acc2 + acc3)) * dn;

  sh[w][lane] = acc;
  __syncthreads();

  float t = b2[lane];
#pragma unroll 16
  for (int j = 0; j < 64; ++j) t += sh[w][j] * W2[j * 64 + lane];
  t = fmaxf(t, 0.0f);

  float p0 = t * Wf[lane * 2 + 0];
  float p1 = t * Wf[lane * 2 + 1];
  for (int off = 32; off; off >>= 1) {
    p0 += __shfl_down(p0, off);
    p1 += __shfl_down(p1, off);
  }
  if (lane == 0) {
    out[n * 2 + 0] = p0 + bf[0];
    out[n * 2 + 1] = p1 + bf[1];
  }
}

// ---------------- launch ----------------

extern "C" void kernel_launch(void* const* d_in, const int* in_sizes, int n_in,
                              void* d_out, int out_size, void* d_ws, size_t ws_size,
                              hipStream_t stream) {
  const float* x  = (const float*)d_in[0];
  const int*   ei = (const int*)d_in[1];     // [2, E] row-major, int32
  const float* W1 = (const float*)d_in[2];
  const float* b1 = (const float*)d_in[3];
  const float* W2 = (const float*)d_in[4];
  const float* b2 = (const float*)d_in[5];
  const float* Wf = (const float*)d_in[6];
  const float* bf = (const float*)d_in[7];
  float* out = (float*)d_out;

  const int* srcv = ei;
  const int* dstv = ei + N_EDGES;

  char* p = (char*)d_ws;
  auto take = [&](size_t bytes) { char* r = p; p += (bytes + 255) & ~(size_t)255; return r; };
  int*          gcur = (int*)take((size_t)NBUCKET * 4);
  unsigned int* eb   = (unsigned int*)take((size_t)NBUCKET * BCAP * 4);  // 13.6 MB, becomes csr
  int*          rs   = (int*)take((size_t)N_NODES * 4);
  int*          re   = (int*)take((size_t)N_NODES * 4);
  float*        dis  = (float*)take((size_t)N_NODES * 4);
  float*        agg1 = (float*)take((size_t)N_NODES * 16);
  __hip_bfloat16* h1s = (__hip_bfloat16*)take((size_t)N_NODES * 64 * 2);  // 12.8 MB

  (void)hipMemsetAsync(gcur, 0, (size_t)NBUCKET * 4, stream);
  k_pass1<<<NPB, 256, 0, stream>>>(srcv, dstv, gcur, eb);
  k_part2<<<NBUCKET, 256, 0, stream>>>(eb, gcur, rs, re, dis);
  const int* csr = (const int*)eb;
  k_agg1 <<<NB, 256, 0, stream>>>((const float4*)x, dis, rs, re, csr, (float4*)agg1);
  k_xform1<<<(N_NODES * 64 + 255) / 256, 256, 0, stream>>>((const float4*)agg1, W1, b1, dis, h1s);
  k_layer2<<<N_NODES / 4, 256, 0, stream>>>(h1s, dis, rs, re, csr, W2, b2, Wf, bf, out);
}

// Round 6
// 288.717 us; speedup vs baseline: 2.7631x; 1.1144x over previous
//
#include <hip/hip_runtime.h>
#include <hip/hip_bf16.h>

#define N_NODES 100000
#define N_EDGES 3200000
#define NB ((N_NODES + 255) / 256)   // 391
#define NBUCKET NB                   // coarse bucket = dst>>8
#define EPB 8192                     // edges per k_pass1 block
#define NPB ((N_EDGES + EPB - 1) / EPB)  // 391 blocks
#define BCAP 11264                   // per-bucket capacity incl. self+pad (mean ~10500, +6σ); 16-aligned

// ---------------- pass 1: LDS-staged coarse partition ----------------
// item: bits[16:0] = src, bits[24:17] = dst & 255. bucket = dst>>8.

__global__ void __launch_bounds__(256) k_pass1(const int* __restrict__ src,
                                               const int* __restrict__ dst,
                                               int* __restrict__ gcur,
                                               unsigned int* __restrict__ eb) {
  __shared__ unsigned int sdata[EPB];
  __shared__ unsigned short sbid[EPB];
  __shared__ int hist[NBUCKET], cur[NBUCKET], gbase[NBUCKET];
  int tid = threadIdx.x;
  int base = blockIdx.x * EPB;
  int cnt = min(EPB, N_EDGES - base);   // always a multiple of 4
  for (int i = tid; i < NBUCKET; i += 256) { hist[i] = 0; cur[i] = 0; }
  __syncthreads();
  const int4* d4 = (const int4*)(dst + base);
  const int4* s4 = (const int4*)(src + base);
  for (int i = tid; i < (cnt >> 2); i += 256) {
    int4 dv = d4[i];
    int4 sv = s4[i];
    int j = i << 2;
    int b0 = dv.x >> 8, b1 = dv.y >> 8, b2 = dv.z >> 8, b3 = dv.w >> 8;
    sdata[j + 0] = (unsigned)sv.x | ((unsigned)(dv.x & 255) << 17);
    sdata[j + 1] = (unsigned)sv.y | ((unsigned)(dv.y & 255) << 17);
    sdata[j + 2] = (unsigned)sv.z | ((unsigned)(dv.z & 255) << 17);
    sdata[j + 3] = (unsigned)sv.w | ((unsigned)(dv.w & 255) << 17);
    sbid[j + 0] = (unsigned short)b0;
    sbid[j + 1] = (unsigned short)b1;
    sbid[j + 2] = (unsigned short)b2;
    sbid[j + 3] = (unsigned short)b3;
    atomicAdd(&hist[b0], 1);
    atomicAdd(&hist[b1], 1);
    atomicAdd(&hist[b2], 1);
    atomicAdd(&hist[b3], 1);
  }
  __syncthreads();
  for (int b = tid; b < NBUCKET; b += 256) {
    int h = hist[b];
    if (h) gbase[b] = atomicAdd(&gcur[b], h);   // one claim per (block,bucket)
  }
  __syncthreads();
  for (int i = tid; i < cnt; i += 256) {
    int b = sbid[i];
    int pos = gbase[b] + atomicAdd(&cur[b], 1);
    eb[b * BCAP + pos] = sdata[i];
  }
}

// ---------------- pass 2: per-bucket counting sort + self-edge + pad-to-16 -------
// Bucket b owns nodes [b*256, b*256+256). Node n's run: [rs[n], re[n]) real
// (self edge first), then pad entries == N_NODES up to a multiple of 16.

__global__ void __launch_bounds__(256) k_part2(unsigned int* __restrict__ eb,
                                               const int* __restrict__ gcur,
                                               int* __restrict__ rs, int* __restrict__ re,
                                               float* __restrict__ dis) {
  __shared__ int hist[256], scn[256], cur[256];
  __shared__ int tot;
  __shared__ unsigned int stage[BCAP];
  int b = blockIdx.x, tid = threadIdx.x;
  int n0 = b << 8;
  int cnt = gcur[b];
  int base = b * BCAP;
  hist[tid] = 0; cur[tid] = 0;
  __syncthreads();
  for (int i = tid; i < cnt; i += 256)
    atomicAdd(&hist[eb[base + i] >> 17], 1);
  __syncthreads();
  int n = n0 + tid;
  int deg = hist[tid];
  int slots = (n < N_NODES) ? ((deg + 1 + 15) & ~15) : 0;
  int x = slots;
  scn[tid] = x;
  __syncthreads();
  for (int off = 1; off < 256; off <<= 1) {
    int t = (tid >= off) ? scn[tid - off] : 0;
    __syncthreads();
    x += t; scn[tid] = x;
    __syncthreads();
  }
  int excl = x - slots;
  if (tid == 255) tot = x;
  if (n < N_NODES) {
    rs[n]  = base + excl;
    re[n]  = base + excl + deg + 1;
    dis[n] = rsqrtf((float)(deg + 1));
    stage[excl] = (unsigned)n;                    // self edge
    for (int i = deg + 1; i < slots; ++i)
      stage[excl + i] = (unsigned)N_NODES;        // zero-row pads
  }
  scn[tid] = excl + 1;                            // in-edge start
  __syncthreads();
  for (int i = tid; i < cnt; i += 256) {
    unsigned v = eb[base + i];
    unsigned low = v >> 17;
    int lpos = scn[low] + atomicAdd(&cur[low], 1);
    stage[lpos] = v & 0x1FFFFu;
  }
  __syncthreads();
  int total = tot;
  for (int i = tid; i < total; i += 256)
    eb[base + i] = stage[i];     // eb is now padded CSR (src ids by dst node)
}

// ---------------- Layer 1: aggregate x (4 feats) then transform ----------------
// Self edge is in the CSR now (uses true re). agg1[n] = dn * sum x[s]*dis[s].

__global__ void k_agg1(const float4* __restrict__ x4, const float* __restrict__ dis,
                       const int* __restrict__ rs, const int* __restrict__ re,
                       const int* __restrict__ csr, float4* __restrict__ agg1) {
  int n = blockIdx.x * blockDim.x + threadIdx.x;
  if (n >= N_NODES) return;
  float dn = dis[n];
  float ax = 0.f, ay = 0.f, az = 0.f, aw = 0.f;
  int e1 = re[n];
  for (int e = rs[n]; e < e1; ++e) {
    int s = csr[e];
    float ds_ = dis[s];
    float4 xs = x4[s];
    ax += xs.x * ds_; ay += xs.y * ds_; az += xs.z * ds_; aw += xs.w * ds_;
  }
  float4 r; r.x = ax * dn; r.y = ay * dn; r.z = az * dn; r.w = aw * dn;
  agg1[n] = r;
}

// h1s[n][j] = bf16( relu(b1[j] + agg1[n]·W1[:,j]) * dis[n] ); row N_NODES = zeros
__global__ void k_xform1(const float4* __restrict__ agg1, const float* __restrict__ W1,
                         const float* __restrict__ b1, const float* __restrict__ dis,
                         __hip_bfloat16* __restrict__ h1s) {
  int t = blockIdx.x * blockDim.x + threadIdx.x;
  if (t >= (N_NODES + 1) * 64) return;
  if (t >= N_NODES * 64) { h1s[t] = __float2bfloat16(0.0f); return; }
  int n = t >> 6, j = t & 63;
  float4 a = agg1[n];
  float s = b1[j] + a.x * W1[j] + a.y * W1[64 + j] + a.z * W1[128 + j] + a.w * W1[192 + j];
  h1s[t] = __float2bfloat16(fmaxf(s, 0.0f) * dis[n]);
}

// ---------------- Layer 2 fused: 4-edges-per-instr gather + MLP + head ----------
// Wave per node. Lane l: g = l>>4 (edge subgroup), c = l&15 (feature chunk of 4).
// Each lane loads dwordx2 = 4 bf16 feats of its subgroup's edge. Padded CSR
// guarantees runs are multiples of 16 (pads hit the zero row at N_NODES).

__device__ inline void acc_bf2(float& a0, float& a1, unsigned u) {
  a0 += __uint_as_float(u << 16);
  a1 += __uint_as_float(u & 0xffff0000u);
}

__global__ void __launch_bounds__(256)
k_layer2(const __hip_bfloat16* __restrict__ h1s, const float* __restrict__ dis,
         const int* __restrict__ rs, const int* __restrict__ re,
         const int* __restrict__ csr,
         const float* __restrict__ W2, const float* __restrict__ b2,
         const float* __restrict__ Wf, const float* __restrict__ bf,
         float* __restrict__ out) {
  __shared__ float sh[4][64];
  int l = threadIdx.x & 63;
  int w = threadIdx.x >> 6;
  int n = blockIdx.x * 4 + w;   // grid = N/4 exactly
  int g = l >> 4;
  int c = l & 15;

  const unsigned int* h32 = (const unsigned int*)h1s;
  int e0 = rs[n];
  int iter = (re[n] - e0 + 15) >> 4;          // padded 16-blocks
  const int4* cp = (const int4*)(csr + e0) + g;  // lane's 4 consecutive edges
  int coff = c << 1;                          // dword offset of feature chunk

  float4 acc = make_float4(0.f, 0.f, 0.f, 0.f);
  for (int it = 0; it < iter; ++it) {
    int4 s4 = *cp;
    cp += 4;   // advance 16 ints
    uint2 u0 = *(const uint2*)(h32 + (s4.x << 5) + coff);
    uint2 u1 = *(const uint2*)(h32 + (s4.y << 5) + coff);
    uint2 u2 = *(const uint2*)(h32 + (s4.z << 5) + coff);
    uint2 u3 = *(const uint2*)(h32 + (s4.w << 5) + coff);
    acc_bf2(acc.x, acc.y, u0.x); acc_bf2(acc.z, acc.w, u0.y);
    acc_bf2(acc.x, acc.y, u1.x); acc_bf2(acc.z, acc.w, u1.y);
    acc_bf2(acc.x, acc.y, u2.x); acc_bf2(acc.z, acc.w, u2.y);
    acc_bf2(acc.x, acc.y, u3.x); acc_bf2(acc.z, acc.w, u3.y);
  }
  // combine the 4 edge-subgroups (lane bits 4,5)
  acc.x += __shfl_xor(acc.x, 16); acc.x += __shfl_xor(acc.x, 32);
  acc.y += __shfl_xor(acc.y, 16); acc.y += __shfl_xor(acc.y, 32);
  acc.z += __shfl_xor(acc.z, 16); acc.z += __shfl_xor(acc.z, 32);
  acc.w += __shfl_xor(acc.w, 16); acc.w += __shfl_xor(acc.w, 32);

  float dn = dis[n];
  if (l < 16) {
    float4 v; v.x = acc.x * dn; v.y = acc.y * dn; v.z = acc.z * dn; v.w = acc.w * dn;
    *(float4*)&sh[w][c << 2] = v;      // agg2[n][4c..4c+3]
  }
  __syncthreads();

  // h2[lane] = relu(b2[lane] + sum_j agg2[j] * W2[j][lane])
  float t = b2[l];
  const float4* shv = (const float4*)sh[w];
#pragma unroll 4
  for (int j4 = 0; j4 < 16; ++j4) {
    float4 a4 = shv[j4];
    t += a4.x * W2[(4 * j4 + 0) * 64 + l];
    t += a4.y * W2[(4 * j4 + 1) * 64 + l];
    t += a4.z * W2[(4 * j4 + 2) * 64 + l];
    t += a4.w * W2[(4 * j4 + 3) * 64 + l];
  }
  t = fmaxf(t, 0.0f);

  float p0 = t * Wf[l * 2 + 0];
  float p1 = t * Wf[l * 2 + 1];
  for (int off = 32; off; off >>= 1) {
    p0 += __shfl_down(p0, off);
    p1 += __shfl_down(p1, off);
  }
  if (l == 0) {
    out[n * 2 + 0] = p0 + bf[0];
    out[n * 2 + 1] = p1 + bf[1];
  }
}

// ---------------- launch ----------------

extern "C" void kernel_launch(void* const* d_in, const int* in_sizes, int n_in,
                              void* d_out, int out_size, void* d_ws, size_t ws_size,
                              hipStream_t stream) {
  const float* x  = (const float*)d_in[0];
  const int*   ei = (const int*)d_in[1];     // [2, E] row-major, int32
  const float* W1 = (const float*)d_in[2];
  const float* b1 = (const float*)d_in[3];
  const float* W2 = (const float*)d_in[4];
  const float* b2 = (const float*)d_in[5];
  const float* Wf = (const float*)d_in[6];
  const float* bf = (const float*)d_in[7];
  float* out = (float*)d_out;

  const int* srcv = ei;
  const int* dstv = ei + N_EDGES;

  char* p = (char*)d_ws;
  auto take = [&](size_t bytes) { char* r = p; p += (bytes + 255) & ~(size_t)255; return r; };
  int*          gcur = (int*)take((size_t)NBUCKET * 4);
  unsigned int* eb   = (unsigned int*)take((size_t)NBUCKET * BCAP * 4 + 256);  // 17.6 MB, becomes padded CSR
  int*          rs   = (int*)take((size_t)N_NODES * 4);
  int*          re   = (int*)take((size_t)N_NODES * 4);
  float*        dis  = (float*)take((size_t)N_NODES * 4);
  float*        agg1 = (float*)take((size_t)N_NODES * 16);
  __hip_bfloat16* h1s = (__hip_bfloat16*)take((size_t)(N_NODES + 1) * 64 * 2); // +zero row

  (void)hipMemsetAsync(gcur, 0, (size_t)NBUCKET * 4, stream);
  k_pass1<<<NPB, 256, 0, stream>>>(srcv, dstv, gcur, eb);
  k_part2<<<NBUCKET, 256, 0, stream>>>(eb, gcur, rs, re, dis);
  const int* csr = (const int*)eb;
  k_agg1 <<<NB, 256, 0, stream>>>((const float4*)x, dis, rs, re, csr, (float4*)agg1);
  k_xform1<<<((N_NODES + 1) * 64 + 255) / 256, 256, 0, stream>>>((const float4*)agg1, W1, b1, dis, h1s);
  k_layer2<<<N_NODES / 4, 256, 0, stream>>>(h1s, dis, rs, re, csr, W2, b2, Wf, bf, out);
}

// Round 7
// 287.249 us; speedup vs baseline: 2.7773x; 1.0051x over previous
//
#include <hip/hip_runtime.h>
#include <hip/hip_bf16.h>

#define N_NODES 100000
#define N_EDGES 3200000
#define NB ((N_NODES + 255) / 256)   // 391
#define NBUCKET NB                   // coarse bucket = dst>>8
#define EPB 8192                     // edges per k_pass1 block
#define NPB ((N_EDGES + EPB - 1) / EPB)  // 391 blocks
#define BCAP 11264                   // per-bucket capacity incl. self+pad+guard; 16-aligned

// ---------------- pass 1: LDS-staged coarse partition ----------------
// item: bits[16:0] = src, bits[24:17] = dst & 255. bucket = dst>>8.

__global__ void __launch_bounds__(256) k_pass1(const int* __restrict__ src,
                                               const int* __restrict__ dst,
                                               int* __restrict__ gcur,
                                               unsigned int* __restrict__ eb) {
  __shared__ unsigned int sdata[EPB];
  __shared__ unsigned short sbid[EPB];
  __shared__ int hist[NBUCKET], cur[NBUCKET], gbase[NBUCKET];
  int tid = threadIdx.x;
  int base = blockIdx.x * EPB;
  int cnt = min(EPB, N_EDGES - base);   // always a multiple of 4
  for (int i = tid; i < NBUCKET; i += 256) { hist[i] = 0; cur[i] = 0; }
  __syncthreads();
  const int4* d4 = (const int4*)(dst + base);
  const int4* s4 = (const int4*)(src + base);
  for (int i = tid; i < (cnt >> 2); i += 256) {
    int4 dv = d4[i];
    int4 sv = s4[i];
    int j = i << 2;
    int b0 = dv.x >> 8, b1 = dv.y >> 8, b2 = dv.z >> 8, b3 = dv.w >> 8;
    sdata[j + 0] = (unsigned)sv.x | ((unsigned)(dv.x & 255) << 17);
    sdata[j + 1] = (unsigned)sv.y | ((unsigned)(dv.y & 255) << 17);
    sdata[j + 2] = (unsigned)sv.z | ((unsigned)(dv.z & 255) << 17);
    sdata[j + 3] = (unsigned)sv.w | ((unsigned)(dv.w & 255) << 17);
    sbid[j + 0] = (unsigned short)b0;
    sbid[j + 1] = (unsigned short)b1;
    sbid[j + 2] = (unsigned short)b2;
    sbid[j + 3] = (unsigned short)b3;
    atomicAdd(&hist[b0], 1);
    atomicAdd(&hist[b1], 1);
    atomicAdd(&hist[b2], 1);
    atomicAdd(&hist[b3], 1);
  }
  __syncthreads();
  for (int b = tid; b < NBUCKET; b += 256) {
    int h = hist[b];
    if (h) gbase[b] = atomicAdd(&gcur[b], h);   // one claim per (block,bucket)
  }
  __syncthreads();
  for (int i = tid; i < cnt; i += 256) {
    int b = sbid[i];
    int pos = gbase[b] + atomicAdd(&cur[b], 1);
    eb[b * BCAP + pos] = sdata[i];
  }
}

// ---------------- pass 2: per-bucket counting sort + self-edge + pad-to-16 -------
// Bucket b owns nodes [b*256, b*256+256). Node n's run: [rs[n], re[n]) real
// (self edge first), pad entries == N_NODES up to a multiple of 16, plus a
// 32-entry guard pad after the bucket's total (for layer2's 2-ahead prefetch).

__global__ void __launch_bounds__(256) k_part2(unsigned int* __restrict__ eb,
                                               const int* __restrict__ gcur,
                                               int* __restrict__ rs, int* __restrict__ re,
                                               float* __restrict__ dis) {
  __shared__ int hist[256], scn[256], cur[256];
  __shared__ int tot;
  __shared__ unsigned int stage[BCAP];
  int b = blockIdx.x, tid = threadIdx.x;
  int n0 = b << 8;
  int cnt = gcur[b];
  int base = b * BCAP;
  hist[tid] = 0; cur[tid] = 0;
  __syncthreads();
  for (int i = tid; i < cnt; i += 256)
    atomicAdd(&hist[eb[base + i] >> 17], 1);
  __syncthreads();
  int n = n0 + tid;
  int deg = hist[tid];
  int slots = (n < N_NODES) ? ((deg + 1 + 15) & ~15) : 0;
  int x = slots;
  scn[tid] = x;
  __syncthreads();
  for (int off = 1; off < 256; off <<= 1) {
    int t = (tid >= off) ? scn[tid - off] : 0;
    __syncthreads();
    x += t; scn[tid] = x;
    __syncthreads();
  }
  int excl = x - slots;
  if (tid == 255) tot = x;
  if (n < N_NODES) {
    rs[n]  = base + excl;
    re[n]  = base + excl + deg + 1;
    dis[n] = rsqrtf((float)(deg + 1));
    stage[excl] = (unsigned)n;                    // self edge
    for (int i = deg + 1; i < slots; ++i)
      stage[excl + i] = (unsigned)N_NODES;        // zero-row pads
  }
  scn[tid] = excl + 1;                            // in-edge start
  __syncthreads();
  for (int i = tid; i < cnt; i += 256) {
    unsigned v = eb[base + i];
    unsigned low = v >> 17;
    int lpos = scn[low] + atomicAdd(&cur[low], 1);
    stage[lpos] = v & 0x1FFFFu;
  }
  __syncthreads();
  int total = tot;
  for (int i = tid; i < total; i += 256)
    eb[base + i] = stage[i];     // eb is now padded CSR (src ids by dst node)
  // guard pads for layer2's prefetch over-read (kept in-bounds by BCAP margin)
  if (tid < 32) {
    int gp = total + tid;
    if (gp < BCAP) eb[base + gp] = (unsigned)N_NODES;
  }
}

// ---------------- Layer 1: aggregate x (4 feats) then transform ----------------

__global__ void k_agg1(const float4* __restrict__ x4, const float* __restrict__ dis,
                       const int* __restrict__ rs, const int* __restrict__ re,
                       const int* __restrict__ csr, float4* __restrict__ agg1) {
  int n = blockIdx.x * blockDim.x + threadIdx.x;
  if (n >= N_NODES) return;
  float dn = dis[n];
  float ax = 0.f, ay = 0.f, az = 0.f, aw = 0.f;
  int e1 = re[n];
  for (int e = rs[n]; e < e1; ++e) {
    int s = csr[e];
    float ds_ = dis[s];
    float4 xs = x4[s];
    ax += xs.x * ds_; ay += xs.y * ds_; az += xs.z * ds_; aw += xs.w * ds_;
  }
  float4 r; r.x = ax * dn; r.y = ay * dn; r.z = az * dn; r.w = aw * dn;
  agg1[n] = r;
}

// h1s[n][j] = bf16( relu(b1[j] + agg1[n]·W1[:,j]) * dis[n] ); row N_NODES = zeros
__global__ void k_xform1(const float4* __restrict__ agg1, const float* __restrict__ W1,
                         const float* __restrict__ b1, const float* __restrict__ dis,
                         __hip_bfloat16* __restrict__ h1s) {
  int t = blockIdx.x * blockDim.x + threadIdx.x;
  if (t >= (N_NODES + 1) * 64) return;
  if (t >= N_NODES * 64) { h1s[t] = __float2bfloat16(0.0f); return; }
  int n = t >> 6, j = t & 63;
  float4 a = agg1[n];
  float s = b1[j] + a.x * W1[j] + a.y * W1[64 + j] + a.z * W1[128 + j] + a.w * W1[192 + j];
  h1s[t] = __float2bfloat16(fmaxf(s, 0.0f) * dis[n]);
}

// ---------------- Layer 2 fused: pipelined 4-edges-per-instr gather + MLP -------
// Wave per node. Lane l: g = l>>4 (edge subgroup), c = l&15 (feature chunk of 4).
// Software pipeline: csr int4 prefetched 2 blocks ahead, row-gathers 1 block
// ahead; the accumulate's waitcnt leaves 5 younger loads in flight.

__device__ inline void acc_bf2(float& a0, float& a1, unsigned u) {
  a0 += __uint_as_float(u << 16);
  a1 += __uint_as_float(u & 0xffff0000u);
}

__global__ void __launch_bounds__(256)
k_layer2(const __hip_bfloat16* __restrict__ h1s, const float* __restrict__ dis,
         const int* __restrict__ rs, const int* __restrict__ re,
         const int* __restrict__ csr,
         const float* __restrict__ W2, const float* __restrict__ b2,
         const float* __restrict__ Wf, const float* __restrict__ bf,
         float* __restrict__ out) {
  __shared__ float sh[4][64];
  int l = threadIdx.x & 63;
  int w = threadIdx.x >> 6;
  int n = blockIdx.x * 4 + w;   // grid = N/4 exactly
  int g = l >> 4;
  int c = l & 15;

  const unsigned int* h32 = (const unsigned int*)h1s;
  int e0 = rs[n];
  int iter = (re[n] - e0 + 15) >> 4;          // padded 16-blocks, >= 1
  const int4* cp = (const int4*)(csr + e0) + g;
  int coff = c << 1;                          // dword offset of feature chunk

  float4 acc = make_float4(0.f, 0.f, 0.f, 0.f);
  // prologue: block 0 gathers + block 1 csr
  int4 ns = cp[4];                            // block 1 (guard-safe)
  int4 cs = cp[0];
  uint2 u0 = *(const uint2*)(h32 + (cs.x << 5) + coff);
  uint2 u1 = *(const uint2*)(h32 + (cs.y << 5) + coff);
  uint2 u2 = *(const uint2*)(h32 + (cs.z << 5) + coff);
  uint2 u3 = *(const uint2*)(h32 + (cs.w << 5) + coff);
  for (int it = 1; it < iter; ++it) {
    int4 fs = cp[(it + 1) << 2];              // 2-ahead csr (guard-safe)
    uint2 n0 = *(const uint2*)(h32 + (ns.x << 5) + coff);
    uint2 n1 = *(const uint2*)(h32 + (ns.y << 5) + coff);
    uint2 n2 = *(const uint2*)(h32 + (ns.z << 5) + coff);
    uint2 n3 = *(const uint2*)(h32 + (ns.w << 5) + coff);
    acc_bf2(acc.x, acc.y, u0.x); acc_bf2(acc.z, acc.w, u0.y);
    acc_bf2(acc.x, acc.y, u1.x); acc_bf2(acc.z, acc.w, u1.y);
    acc_bf2(acc.x, acc.y, u2.x); acc_bf2(acc.z, acc.w, u2.y);
    acc_bf2(acc.x, acc.y, u3.x); acc_bf2(acc.z, acc.w, u3.y);
    u0 = n0; u1 = n1; u2 = n2; u3 = n3;
    ns = fs;
  }
  acc_bf2(acc.x, acc.y, u0.x); acc_bf2(acc.z, acc.w, u0.y);
  acc_bf2(acc.x, acc.y, u1.x); acc_bf2(acc.z, acc.w, u1.y);
  acc_bf2(acc.x, acc.y, u2.x); acc_bf2(acc.z, acc.w, u2.y);
  acc_bf2(acc.x, acc.y, u3.x); acc_bf2(acc.z, acc.w, u3.y);

  // combine the 4 edge-subgroups (lane bits 4,5)
  acc.x += __shfl_xor(acc.x, 16); acc.x += __shfl_xor(acc.x, 32);
  acc.y += __shfl_xor(acc.y, 16); acc.y += __shfl_xor(acc.y, 32);
  acc.z += __shfl_xor(acc.z, 16); acc.z += __shfl_xor(acc.z, 32);
  acc.w += __shfl_xor(acc.w, 16); acc.w += __shfl_xor(acc.w, 32);

  float dn = dis[n];
  if (l < 16) {
    float4 v; v.x = acc.x * dn; v.y = acc.y * dn; v.z = acc.z * dn; v.w = acc.w * dn;
    *(float4*)&sh[w][c << 2] = v;      // agg2[n][4c..4c+3]
  }
  __syncthreads();

  // h2[lane] = relu(b2[lane] + sum_j agg2[j] * W2[j][lane])
  float t = b2[l];
  const float4* shv = (const float4*)sh[w];
#pragma unroll 4
  for (int j4 = 0; j4 < 16; ++j4) {
    float4 a4 = shv[j4];
    t += a4.x * W2[(4 * j4 + 0) * 64 + l];
    t += a4.y * W2[(4 * j4 + 1) * 64 + l];
    t += a4.z * W2[(4 * j4 + 2) * 64 + l];
    t += a4.w * W2[(4 * j4 + 3) * 64 + l];
  }
  t = fmaxf(t, 0.0f);

  float p0 = t * Wf[l * 2 + 0];
  float p1 = t * Wf[l * 2 + 1];
  for (int off = 32; off; off >>= 1) {
    p0 += __shfl_down(p0, off);
    p1 += __shfl_down(p1, off);
  }
  if (l == 0) {
    out[n * 2 + 0] = p0 + bf[0];
    out[n * 2 + 1] = p1 + bf[1];
  }
}

// ---------------- launch ----------------

extern "C" void kernel_launch(void* const* d_in, const int* in_sizes, int n_in,
                              void* d_out, int out_size, void* d_ws, size_t ws_size,
                              hipStream_t stream) {
  const float* x  = (const float*)d_in[0];
  const int*   ei = (const int*)d_in[1];     // [2, E] row-major, int32
  const float* W1 = (const float*)d_in[2];
  const float* b1 = (const float*)d_in[3];
  const float* W2 = (const float*)d_in[4];
  const float* b2 = (const float*)d_in[5];
  const float* Wf = (const float*)d_in[6];
  const float* bf = (const float*)d_in[7];
  float* out = (float*)d_out;

  const int* srcv = ei;
  const int* dstv = ei + N_EDGES;

  char* p = (char*)d_ws;
  auto take = [&](size_t bytes) { char* r = p; p += (bytes + 255) & ~(size_t)255; return r; };
  int*          gcur = (int*)take((size_t)NBUCKET * 4);
  unsigned int* eb   = (unsigned int*)take((size_t)NBUCKET * BCAP * 4 + 512);  // padded CSR (+ tail slack)
  int*          rs   = (int*)take((size_t)N_NODES * 4);
  int*          re   = (int*)take((size_t)N_NODES * 4);
  float*        dis  = (float*)take((size_t)N_NODES * 4);
  float*        agg1 = (float*)take((size_t)N_NODES * 16);
  __hip_bfloat16* h1s = (__hip_bfloat16*)take((size_t)(N_NODES + 1) * 64 * 2); // +zero row

  (void)hipMemsetAsync(gcur, 0, (size_t)NBUCKET * 4, stream);
  k_pass1<<<NPB, 256, 0, stream>>>(srcv, dstv, gcur, eb);
  k_part2<<<NBUCKET, 256, 0, stream>>>(eb, gcur, rs, re, dis);
  const int* csr = (const int*)eb;
  k_agg1 <<<NB, 256, 0, stream>>>((const float4*)x, dis, rs, re, csr, (float4*)agg1);
  k_xform1<<<((N_NODES + 1) * 64 + 255) / 256, 256, 0, stream>>>((const float4*)agg1, W1, b1, dis, h1s);
  k_layer2<<<N_NODES / 4, 256, 0, stream>>>(h1s, dis, rs, re, csr, W2, b2, Wf, bf, out);
}

// Round 8
// 250.498 us; speedup vs baseline: 3.1847x; 1.1467x over previous
//
#include <hip/hip_runtime.h>
#include <hip/hip_bf16.h>

#define N_NODES 100000
#define N_EDGES 3200000
#define NB ((N_NODES + 255) / 256)   // 391
#define NBUCKET NB                   // coarse bucket = dst>>8
#define EPB 8192                     // edges per k_pass1 block
#define NPB ((N_EDGES + EPB - 1) / EPB)  // 391 blocks
#define BCAP 11264                   // per-bucket capacity incl. self+pad+guard; 16-aligned

// RNE float->bf16 bits (matches __float2bfloat16 for finite values)
__device__ inline unsigned f2bf(float f) {
  unsigned x = __float_as_uint(f);
  return (x + 0x7FFFu + ((x >> 16) & 1u)) >> 16;
}

// ---------------- pass 1: register-resident coarse partition ----------------
// item: bits[16:0] = src, bits[24:17] = dst & 255 (bucket = dst>>8).
// Single LDS-atomic round: per-item position packed into bits[31:25].

__global__ void __launch_bounds__(256) k_pass1(const int* __restrict__ src,
                                               const int* __restrict__ dst,
                                               int* __restrict__ gcur,
                                               unsigned int* __restrict__ eb) {
  __shared__ int hist[NBUCKET];
  __shared__ int gbase[NBUCKET];
  int tid = threadIdx.x;
  int base = blockIdx.x * EPB;
  int cnt = min(EPB, N_EDGES - base);   // multiple of 4
  int n4 = cnt >> 2;
  for (int i = tid; i < NBUCKET; i += 256) hist[i] = 0;
  __syncthreads();
  const int4* d4 = (const int4*)(dst + base);
  const int4* s4 = (const int4*)(src + base);
  unsigned mv[32];
  unsigned short mb[32];
#pragma unroll
  for (int k = 0; k < 8; ++k) {
    int i = tid + (k << 8);
    if (i < n4) {
      int4 dv = d4[i];
      int4 sv = s4[i];
      int b0 = dv.x >> 8, b1_ = dv.y >> 8, b2 = dv.z >> 8, b3 = dv.w >> 8;
      unsigned p0 = atomicAdd(&hist[b0], 1);
      unsigned p1 = atomicAdd(&hist[b1_], 1);
      unsigned p2 = atomicAdd(&hist[b2], 1);
      unsigned p3 = atomicAdd(&hist[b3], 1);
      mv[4 * k + 0] = (unsigned)sv.x | ((unsigned)(dv.x & 255) << 17) | (p0 << 25);
      mv[4 * k + 1] = (unsigned)sv.y | ((unsigned)(dv.y & 255) << 17) | (p1 << 25);
      mv[4 * k + 2] = (unsigned)sv.z | ((unsigned)(dv.z & 255) << 17) | (p2 << 25);
      mv[4 * k + 3] = (unsigned)sv.w | ((unsigned)(dv.w & 255) << 17) | (p3 << 25);
      mb[4 * k + 0] = (unsigned short)b0;
      mb[4 * k + 1] = (unsigned short)b1_;
      mb[4 * k + 2] = (unsigned short)b2;
      mb[4 * k + 3] = (unsigned short)b3;
    } else {
      mb[4 * k + 0] = 0xFFFF; mb[4 * k + 1] = 0xFFFF;
      mb[4 * k + 2] = 0xFFFF; mb[4 * k + 3] = 0xFFFF;
    }
  }
  __syncthreads();
  for (int b = tid; b < NBUCKET; b += 256) {
    int h = hist[b];
    gbase[b] = h ? atomicAdd(&gcur[b], h) : 0;   // one claim per (block,bucket)
  }
  __syncthreads();
#pragma unroll
  for (int k = 0; k < 32; ++k) {
    if (mb[k] != 0xFFFF) {
      int b = mb[k];
      unsigned v = mv[k];
      unsigned pos = (unsigned)gbase[b] + (v >> 25);
      if (pos < BCAP) eb[(size_t)b * BCAP + pos] = v & 0x01FFFFFFu;
    }
  }
}

// ---------------- pass 2: per-bucket counting sort + self-edge + pad-to-16 -------
// Also emits dis[n] and xd[n] = x4[n]*dis[n] (plus zero row xd[N_NODES]).

__global__ void __launch_bounds__(256) k_part2(unsigned int* __restrict__ eb,
                                               const int* __restrict__ gcur,
                                               int* __restrict__ rs, int* __restrict__ re,
                                               float* __restrict__ dis,
                                               const float4* __restrict__ x4,
                                               float4* __restrict__ xd) {
  __shared__ int hist[256], scn[256], cur[256];
  __shared__ int tot;
  __shared__ unsigned int stage[BCAP];
  int b = blockIdx.x, tid = threadIdx.x;
  int n0 = b << 8;
  int cnt = gcur[b];
  int base = b * BCAP;
  hist[tid] = 0; cur[tid] = 0;
  __syncthreads();
  for (int i = tid; i < cnt; i += 256)
    atomicAdd(&hist[eb[base + i] >> 17], 1);
  __syncthreads();
  int n = n0 + tid;
  int deg = hist[tid];
  int slots = (n < N_NODES) ? ((deg + 1 + 15) & ~15) : 0;
  int x = slots;
  scn[tid] = x;
  __syncthreads();
  for (int off = 1; off < 256; off <<= 1) {
    int t = (tid >= off) ? scn[tid - off] : 0;
    __syncthreads();
    x += t; scn[tid] = x;
    __syncthreads();
  }
  int excl = x - slots;
  if (tid == 255) tot = x;
  if (n < N_NODES) {
    rs[n]  = base + excl;
    re[n]  = base + excl + deg + 1;
    float dn = rsqrtf((float)(deg + 1));
    dis[n] = dn;
    float4 xv = x4[n];
    float4 w; w.x = xv.x * dn; w.y = xv.y * dn; w.z = xv.z * dn; w.w = xv.w * dn;
    xd[n] = w;
    stage[excl] = (unsigned)n;                    // self edge
    for (int i = deg + 1; i < slots; ++i)
      stage[excl + i] = (unsigned)N_NODES;        // zero-row pads
  }
  if (b == 0 && tid == 0) xd[N_NODES] = make_float4(0.f, 0.f, 0.f, 0.f);
  scn[tid] = excl + 1;                            // in-edge start
  __syncthreads();
  for (int i = tid; i < cnt; i += 256) {
    unsigned v = eb[base + i];
    unsigned low = v >> 17;
    int lpos = scn[low] + atomicAdd(&cur[low], 1);
    stage[lpos] = v & 0x1FFFFu;
  }
  __syncthreads();
  int total = tot;
  for (int i = tid; i < total; i += 256)
    eb[base + i] = stage[i];     // eb is now padded CSR (src ids by dst node)
  if (tid < 32) {                // guard pads for layer2's 2-ahead prefetch
    int gp = total + tid;
    if (gp < BCAP) eb[base + gp] = (unsigned)N_NODES;
  }
}

// ---------------- Layer 1 fused: aggregate xd + transform + bf16 store ----------
// 4 threads per node (p = gt&3). Thread p sums int4-blocks p, p+4, ... of the
// padded CSR (pads hit xd's zero row), shfl_xor combine, then writes feature
// slice [16p, 16p+16) of h1s[n] = bf16(relu(b1 + agg·W1) * dis[n]).

__global__ void __launch_bounds__(256) k_l1(const float4* __restrict__ xd,
                                            const float* __restrict__ dis,
                                            const int* __restrict__ rs,
                                            const int* __restrict__ re,
                                            const int* __restrict__ csr,
                                            const float* __restrict__ W1,
                                            const float* __restrict__ b1,
                                            unsigned int* __restrict__ h1o) {
  int gt = blockIdx.x * 256 + threadIdx.x;
  int nid = gt >> 2, p = gt & 3;
  if (nid > N_NODES) return;
  if (nid == N_NODES) {                       // zero row (pad target for layer2)
    uint4 z = make_uint4(0u, 0u, 0u, 0u);
    uint4* op = (uint4*)(h1o + nid * 32 + p * 8);
    op[0] = z; op[1] = z;
    return;
  }
  int e0 = rs[nid];
  int nbk = (re[nid] - e0 + 15) >> 4;
  const int4* cp = (const int4*)(csr + e0) + p;
  float ax = 0.f, ay = 0.f, az = 0.f, aw = 0.f;
  for (int t = 0; t < nbk; ++t) {
    int4 s4 = cp[t << 2];
    float4 v0 = xd[s4.x];
    float4 v1 = xd[s4.y];
    float4 v2 = xd[s4.z];
    float4 v3 = xd[s4.w];
    ax += (v0.x + v1.x) + (v2.x + v3.x);
    ay += (v0.y + v1.y) + (v2.y + v3.y);
    az += (v0.z + v1.z) + (v2.z + v3.z);
    aw += (v0.w + v1.w) + (v2.w + v3.w);
  }
  ax += __shfl_xor(ax, 1); ax += __shfl_xor(ax, 2);
  ay += __shfl_xor(ay, 1); ay += __shfl_xor(ay, 2);
  az += __shfl_xor(az, 1); az += __shfl_xor(az, 2);
  aw += __shfl_xor(aw, 1); aw += __shfl_xor(aw, 2);
  float dn = dis[nid];
  ax *= dn; ay *= dn; az *= dn; aw *= dn;     // agg1[nid]
  int j0 = p << 4;
  unsigned ou[8];
#pragma unroll
  for (int j2 = 0; j2 < 8; ++j2) {
    int j = j0 + j2 * 2;
    float s0 = b1[j]     + ax * W1[j]     + ay * W1[64 + j]     + az * W1[128 + j]     + aw * W1[192 + j];
    float s1 = b1[j + 1] + ax * W1[j + 1] + ay * W1[64 + j + 1] + az * W1[128 + j + 1] + aw * W1[192 + j + 1];
    unsigned u0 = f2bf(fmaxf(s0, 0.f) * dn);
    unsigned u1 = f2bf(fmaxf(s1, 0.f) * dn);
    ou[j2] = u0 | (u1 << 16);
  }
  uint4* op = (uint4*)(h1o + nid * 32 + p * 8);
  op[0] = make_uint4(ou[0], ou[1], ou[2], ou[3]);
  op[1] = make_uint4(ou[4], ou[5], ou[6], ou[7]);
}

// ---------------- Layer 2 fused: pipelined 4-edges-per-instr gather + MLP -------

__device__ inline void acc_bf2(float& a0, float& a1, unsigned u) {
  a0 += __uint_as_float(u << 16);
  a1 += __uint_as_float(u & 0xffff0000u);
}

__global__ void __launch_bounds__(256)
k_layer2(const __hip_bfloat16* __restrict__ h1s, const float* __restrict__ dis,
         const int* __restrict__ rs, const int* __restrict__ re,
         const int* __restrict__ csr,
         const float* __restrict__ W2, const float* __restrict__ b2,
         const float* __restrict__ Wf, const float* __restrict__ bf,
         float* __restrict__ out) {
  __shared__ float sh[4][64];
  int l = threadIdx.x & 63;
  int w = threadIdx.x >> 6;
  int n = blockIdx.x * 4 + w;   // grid = N/4 exactly
  int g = l >> 4;
  int c = l & 15;

  const unsigned int* h32 = (const unsigned int*)h1s;
  int e0 = rs[n];
  int iter = (re[n] - e0 + 15) >> 4;          // padded 16-blocks, >= 1
  const int4* cp = (const int4*)(csr + e0) + g;
  int coff = c << 1;                          // dword offset of feature chunk

  float4 acc = make_float4(0.f, 0.f, 0.f, 0.f);
  int4 ns = cp[4];                            // block 1 (guard-safe)
  int4 cs = cp[0];
  uint2 u0 = *(const uint2*)(h32 + (cs.x << 5) + coff);
  uint2 u1 = *(const uint2*)(h32 + (cs.y << 5) + coff);
  uint2 u2 = *(const uint2*)(h32 + (cs.z << 5) + coff);
  uint2 u3 = *(const uint2*)(h32 + (cs.w << 5) + coff);
  for (int it = 1; it < iter; ++it) {
    int4 fs = cp[(it + 1) << 2];              // 2-ahead csr (guard-safe)
    uint2 n0 = *(const uint2*)(h32 + (ns.x << 5) + coff);
    uint2 n1 = *(const uint2*)(h32 + (ns.y << 5) + coff);
    uint2 n2 = *(const uint2*)(h32 + (ns.z << 5) + coff);
    uint2 n3 = *(const uint2*)(h32 + (ns.w << 5) + coff);
    acc_bf2(acc.x, acc.y, u0.x); acc_bf2(acc.z, acc.w, u0.y);
    acc_bf2(acc.x, acc.y, u1.x); acc_bf2(acc.z, acc.w, u1.y);
    acc_bf2(acc.x, acc.y, u2.x); acc_bf2(acc.z, acc.w, u2.y);
    acc_bf2(acc.x, acc.y, u3.x); acc_bf2(acc.z, acc.w, u3.y);
    u0 = n0; u1 = n1; u2 = n2; u3 = n3;
    ns = fs;
  }
  acc_bf2(acc.x, acc.y, u0.x); acc_bf2(acc.z, acc.w, u0.y);
  acc_bf2(acc.x, acc.y, u1.x); acc_bf2(acc.z, acc.w, u1.y);
  acc_bf2(acc.x, acc.y, u2.x); acc_bf2(acc.z, acc.w, u2.y);
  acc_bf2(acc.x, acc.y, u3.x); acc_bf2(acc.z, acc.w, u3.y);

  acc.x += __shfl_xor(acc.x, 16); acc.x += __shfl_xor(acc.x, 32);
  acc.y += __shfl_xor(acc.y, 16); acc.y += __shfl_xor(acc.y, 32);
  acc.z += __shfl_xor(acc.z, 16); acc.z += __shfl_xor(acc.z, 32);
  acc.w += __shfl_xor(acc.w, 16); acc.w += __shfl_xor(acc.w, 32);

  float dn = dis[n];
  if (l < 16) {
    float4 v; v.x = acc.x * dn; v.y = acc.y * dn; v.z = acc.z * dn; v.w = acc.w * dn;
    *(float4*)&sh[w][c << 2] = v;      // agg2[n][4c..4c+3]
  }
  __syncthreads();

  float t = b2[l];
  const float4* shv = (const float4*)sh[w];
#pragma unroll 4
  for (int j4 = 0; j4 < 16; ++j4) {
    float4 a4 = shv[j4];
    t += a4.x * W2[(4 * j4 + 0) * 64 + l];
    t += a4.y * W2[(4 * j4 + 1) * 64 + l];
    t += a4.z * W2[(4 * j4 + 2) * 64 + l];
    t += a4.w * W2[(4 * j4 + 3) * 64 + l];
  }
  t = fmaxf(t, 0.0f);

  float p0 = t * Wf[l * 2 + 0];
  float p1 = t * Wf[l * 2 + 1];
  for (int off = 32; off; off >>= 1) {
    p0 += __shfl_down(p0, off);
    p1 += __shfl_down(p1, off);
  }
  if (l == 0) {
    out[n * 2 + 0] = p0 + bf[0];
    out[n * 2 + 1] = p1 + bf[1];
  }
}

// ---------------- launch ----------------

extern "C" void kernel_launch(void* const* d_in, const int* in_sizes, int n_in,
                              void* d_out, int out_size, void* d_ws, size_t ws_size,
                              hipStream_t stream) {
  const float* x  = (const float*)d_in[0];
  const int*   ei = (const int*)d_in[1];     // [2, E] row-major, int32
  const float* W1 = (const float*)d_in[2];
  const float* b1 = (const float*)d_in[3];
  const float* W2 = (const float*)d_in[4];
  const float* b2 = (const float*)d_in[5];
  const float* Wf = (const float*)d_in[6];
  const float* bf = (const float*)d_in[7];
  float* out = (float*)d_out;

  const int* srcv = ei;
  const int* dstv = ei + N_EDGES;

  char* p = (char*)d_ws;
  auto take = [&](size_t bytes) { char* r = p; p += (bytes + 255) & ~(size_t)255; return r; };
  int*          gcur = (int*)take((size_t)NBUCKET * 4);
  unsigned int* eb   = (unsigned int*)take((size_t)NBUCKET * BCAP * 4 + 512);  // padded CSR
  int*          rs   = (int*)take((size_t)N_NODES * 4);
  int*          re   = (int*)take((size_t)N_NODES * 4);
  float*        dis  = (float*)take((size_t)N_NODES * 4);
  float4*       xd   = (float4*)take((size_t)(N_NODES + 1) * 16);               // + zero row
  __hip_bfloat16* h1s = (__hip_bfloat16*)take((size_t)(N_NODES + 1) * 64 * 2);  // + zero row

  (void)hipMemsetAsync(gcur, 0, (size_t)NBUCKET * 4, stream);
  k_pass1<<<NPB, 256, 0, stream>>>(srcv, dstv, gcur, eb);
  k_part2<<<NBUCKET, 256, 0, stream>>>(eb, gcur, rs, re, dis, (const float4*)x, xd);
  const int* csr = (const int*)eb;
  k_l1<<<((N_NODES + 1) * 4 + 255) / 256, 256, 0, stream>>>(xd, dis, rs, re, csr, W1, b1, (unsigned int*)h1s);
  k_layer2<<<N_NODES / 4, 256, 0, stream>>>(h1s, dis, rs, re, csr, W2, b2, Wf, bf, out);
}

// Round 9
// 246.646 us; speedup vs baseline: 3.2344x; 1.0156x over previous
//
#include <hip/hip_runtime.h>
#include <hip/hip_bf16.h>

#define N_NODES 100000
#define N_EDGES 3200000
#define NB ((N_NODES + 255) / 256)   // 391
#define NBUCKET NB                   // coarse bucket = dst>>8
#define EPB 8192                     // edges per k_pass1 block
#define NPB ((N_EDGES + EPB - 1) / EPB)  // 391 blocks
#define BCAP 11264                   // per-bucket cap incl self+pad(8)+guard; mean ~9344, 20 sigma

// RNE float->bf16 bits (matches __float2bfloat16 for finite values)
__device__ inline unsigned f2bf(float f) {
  unsigned x = __float_as_uint(f);
  return (x + 0x7FFFu + ((x >> 16) & 1u)) >> 16;
}

// ---------------- pass 1: register-resident coarse partition ----------------
// item: bits[16:0] = src, bits[24:17] = dst & 255 (bucket = dst>>8).
// Single LDS-atomic round: per-item position packed into bits[31:25].

__global__ void __launch_bounds__(256) k_pass1(const int* __restrict__ src,
                                               const int* __restrict__ dst,
                                               int* __restrict__ gcur,
                                               unsigned int* __restrict__ eb) {
  __shared__ int hist[NBUCKET];
  __shared__ int gbase[NBUCKET];
  int tid = threadIdx.x;
  int base = blockIdx.x * EPB;
  int cnt = min(EPB, N_EDGES - base);   // multiple of 4
  int n4 = cnt >> 2;
  for (int i = tid; i < NBUCKET; i += 256) hist[i] = 0;
  __syncthreads();
  const int4* d4 = (const int4*)(dst + base);
  const int4* s4 = (const int4*)(src + base);
  unsigned mv[32];
  unsigned short mb[32];
#pragma unroll
  for (int k = 0; k < 8; ++k) {
    int i = tid + (k << 8);
    if (i < n4) {
      int4 dv = d4[i];
      int4 sv = s4[i];
      int b0 = dv.x >> 8, b1_ = dv.y >> 8, b2 = dv.z >> 8, b3 = dv.w >> 8;
      unsigned p0 = atomicAdd(&hist[b0], 1);
      unsigned p1 = atomicAdd(&hist[b1_], 1);
      unsigned p2 = atomicAdd(&hist[b2], 1);
      unsigned p3 = atomicAdd(&hist[b3], 1);
      mv[4 * k + 0] = (unsigned)sv.x | ((unsigned)(dv.x & 255) << 17) | (p0 << 25);
      mv[4 * k + 1] = (unsigned)sv.y | ((unsigned)(dv.y & 255) << 17) | (p1 << 25);
      mv[4 * k + 2] = (unsigned)sv.z | ((unsigned)(dv.z & 255) << 17) | (p2 << 25);
      mv[4 * k + 3] = (unsigned)sv.w | ((unsigned)(dv.w & 255) << 17) | (p3 << 25);
      mb[4 * k + 0] = (unsigned short)b0;
      mb[4 * k + 1] = (unsigned short)b1_;
      mb[4 * k + 2] = (unsigned short)b2;
      mb[4 * k + 3] = (unsigned short)b3;
    } else {
      mb[4 * k + 0] = 0xFFFF; mb[4 * k + 1] = 0xFFFF;
      mb[4 * k + 2] = 0xFFFF; mb[4 * k + 3] = 0xFFFF;
    }
  }
  __syncthreads();
  for (int b = tid; b < NBUCKET; b += 256) {
    int h = hist[b];
    gbase[b] = h ? atomicAdd(&gcur[b], h) : 0;   // one claim per (block,bucket)
  }
  __syncthreads();
#pragma unroll
  for (int k = 0; k < 32; ++k) {
    if (mb[k] != 0xFFFF) {
      int b = mb[k];
      unsigned v = mv[k];
      unsigned pos = (unsigned)gbase[b] + (v >> 25);
      if (pos < BCAP) eb[(size_t)b * BCAP + pos] = v & 0x01FFFFFFu;
    }
  }
}

// ---------------- pass 2: per-bucket counting sort + self-edge + pad-to-8 --------
// Node n's run: [rs[n], re[n]) real (self first), pads == N_NODES to a multiple
// of 8, 16-entry guard after the bucket total. Also emits dis, xd = x4*dis.

__global__ void __launch_bounds__(256) k_part2(unsigned int* __restrict__ eb,
                                               const int* __restrict__ gcur,
                                               int* __restrict__ rs, int* __restrict__ re,
                                               float* __restrict__ dis,
                                               const float4* __restrict__ x4,
                                               float4* __restrict__ xd) {
  __shared__ int hist[256], scn[256], cur[256];
  __shared__ int tot;
  __shared__ unsigned int stage[BCAP];
  int b = blockIdx.x, tid = threadIdx.x;
  int n0 = b << 8;
  int cnt = gcur[b];
  int base = b * BCAP;
  hist[tid] = 0; cur[tid] = 0;
  __syncthreads();
  for (int i = tid; i < cnt; i += 256)
    atomicAdd(&hist[eb[base + i] >> 17], 1);
  __syncthreads();
  int n = n0 + tid;
  int deg = hist[tid];
  int slots = (n < N_NODES) ? ((deg + 1 + 7) & ~7) : 0;
  int x = slots;
  scn[tid] = x;
  __syncthreads();
  for (int off = 1; off < 256; off <<= 1) {
    int t = (tid >= off) ? scn[tid - off] : 0;
    __syncthreads();
    x += t; scn[tid] = x;
    __syncthreads();
  }
  int excl = x - slots;
  if (tid == 255) tot = x;
  if (n < N_NODES) {
    rs[n]  = base + excl;
    re[n]  = base + excl + deg + 1;
    float dn = rsqrtf((float)(deg + 1));
    dis[n] = dn;
    float4 xv = x4[n];
    float4 w; w.x = xv.x * dn; w.y = xv.y * dn; w.z = xv.z * dn; w.w = xv.w * dn;
    xd[n] = w;
    stage[excl] = (unsigned)n;                    // self edge
    for (int i = deg + 1; i < slots; ++i)
      stage[excl + i] = (unsigned)N_NODES;        // zero-row pads
  }
  if (b == 0 && tid == 0) xd[N_NODES] = make_float4(0.f, 0.f, 0.f, 0.f);
  scn[tid] = excl + 1;                            // in-edge start
  __syncthreads();
  for (int i = tid; i < cnt; i += 256) {
    unsigned v = eb[base + i];
    unsigned low = v >> 17;
    int lpos = scn[low] + atomicAdd(&cur[low], 1);
    stage[lpos] = v & 0x1FFFFu;
  }
  __syncthreads();
  int total = tot;
  for (int i = tid; i < total; i += 256)
    eb[base + i] = stage[i];     // eb is now padded CSR (src ids by dst node)
  if (tid < 16) {                // guard pads for layer2's prefetch over-read
    int gp = total + tid;
    if (gp < BCAP) eb[base + gp] = (unsigned)N_NODES;
  }
}

// ---------------- Layer 1 fused: aggregate xd + transform + bf16 store ----------
// 4 threads per node (p = gt&3). Thread p reads csr dwords e0+4t+p (slots are
// multiples of 8; pads hit xd's zero row), shfl_xor combine, then writes
// feature slice [16p, 16p+16) of h1s[n] = bf16(relu(b1 + agg·W1) * dis[n]).

__global__ void __launch_bounds__(256) k_l1(const float4* __restrict__ xd,
                                            const float* __restrict__ dis,
                                            const int* __restrict__ rs,
                                            const int* __restrict__ re,
                                            const int* __restrict__ csr,
                                            const float* __restrict__ W1,
                                            const float* __restrict__ b1,
                                            unsigned int* __restrict__ h1o) {
  int gt = blockIdx.x * 256 + threadIdx.x;
  int nid = gt >> 2, p = gt & 3;
  if (nid > N_NODES) return;
  if (nid == N_NODES) {                       // zero row (pad target for layer2)
    uint4 z = make_uint4(0u, 0u, 0u, 0u);
    uint4* op = (uint4*)(h1o + nid * 32 + p * 8);
    op[0] = z; op[1] = z;
    return;
  }
  int e0 = rs[nid];
  int it4 = ((re[nid] - e0 + 7) & ~7) >> 2;   // dword quads per thread-pass
  const int* cp = csr + e0 + p;
  float ax = 0.f, ay = 0.f, az = 0.f, aw = 0.f;
#pragma unroll 4
  for (int t = 0; t < it4; ++t) {
    int s = cp[t << 2];
    float4 v = xd[s];
    ax += v.x; ay += v.y; az += v.z; aw += v.w;
  }
  ax += __shfl_xor(ax, 1); ax += __shfl_xor(ax, 2);
  ay += __shfl_xor(ay, 1); ay += __shfl_xor(ay, 2);
  az += __shfl_xor(az, 1); az += __shfl_xor(az, 2);
  aw += __shfl_xor(aw, 1); aw += __shfl_xor(aw, 2);
  float dn = dis[nid];
  ax *= dn; ay *= dn; az *= dn; aw *= dn;     // agg1[nid]
  int j0 = p << 4;
  unsigned ou[8];
#pragma unroll
  for (int j2 = 0; j2 < 8; ++j2) {
    int j = j0 + j2 * 2;
    float s0 = b1[j]     + ax * W1[j]     + ay * W1[64 + j]     + az * W1[128 + j]     + aw * W1[192 + j];
    float s1 = b1[j + 1] + ax * W1[j + 1] + ay * W1[64 + j + 1] + az * W1[128 + j + 1] + aw * W1[192 + j + 1];
    unsigned u0 = f2bf(fmaxf(s0, 0.f) * dn);
    unsigned u1 = f2bf(fmaxf(s1, 0.f) * dn);
    ou[j2] = u0 | (u1 << 16);
  }
  uint4* op = (uint4*)(h1o + nid * 32 + p * 8);
  op[0] = make_uint4(ou[0], ou[1], ou[2], ou[3]);
  op[1] = make_uint4(ou[4], ou[5], ou[6], ou[7]);
}

// ---------------- Layer 2 fused: 8-edge x uint4 pipelined gather + MLP ----------
// Wave per node. Lane l: g = l>>3 (edge subgroup 0..7), c = l&7 (8-feat chunk,
// uint4 = 16 B). 8 rows in flight per wave; csr prefetched 2 blocks ahead
// (over-reads land in the next node's run or the guard — addresses only).

__device__ inline void acc_bf2(float& a0, float& a1, unsigned u) {
  a0 += __uint_as_float(u << 16);
  a1 += __uint_as_float(u & 0xffff0000u);
}

__global__ void __launch_bounds__(256)
k_layer2(const __hip_bfloat16* __restrict__ h1s, const float* __restrict__ dis,
         const int* __restrict__ rs, const int* __restrict__ re,
         const int* __restrict__ csr,
         const float* __restrict__ W2, const float* __restrict__ b2,
         const float* __restrict__ Wf, const float* __restrict__ bf,
         float* __restrict__ out) {
  __shared__ float sh[4][64];
  int l = threadIdx.x & 63;
  int w = threadIdx.x >> 6;
  int n = blockIdx.x * 4 + w;   // grid = N/4 exactly
  int g = l >> 3;
  int c = l & 7;

  const unsigned int* h32 = (const unsigned int*)h1s;
  int e0 = rs[n];
  int iter = (re[n] - e0 + 7) >> 3;           // padded 8-blocks, >= 1
  const int* cb = csr + e0 + g;
  int coff = c << 2;                          // dword offset of feature chunk

  float a0 = 0.f, a1 = 0.f, a2 = 0.f, a3 = 0.f;
  float a4 = 0.f, a5 = 0.f, a6 = 0.f, a7 = 0.f;
  int sc = cb[0];                             // iter 0 edge id
  int sn = cb[8];                             // iter 1 (guard-safe)
  uint4 u = *(const uint4*)(h32 + (sc << 5) + coff);
  for (int it = 1; it < iter; ++it) {
    int sf = cb[(it + 1) << 3];               // 2-ahead csr (guard-safe)
    uint4 r = *(const uint4*)(h32 + (sn << 5) + coff);
    acc_bf2(a0, a1, u.x); acc_bf2(a2, a3, u.y);
    acc_bf2(a4, a5, u.z); acc_bf2(a6, a7, u.w);
    u = r; sn = sf;
  }
  acc_bf2(a0, a1, u.x); acc_bf2(a2, a3, u.y);
  acc_bf2(a4, a5, u.z); acc_bf2(a6, a7, u.w);

  // reduce across the 8 edge-subgroups (lane bits 3,4,5)
#define RED3(a) a += __shfl_xor(a, 8); a += __shfl_xor(a, 16); a += __shfl_xor(a, 32);
  RED3(a0) RED3(a1) RED3(a2) RED3(a3) RED3(a4) RED3(a5) RED3(a6) RED3(a7)
#undef RED3

  float dn = dis[n];
  if (l < 8) {                                // lane l == chunk c: feats 8l..8l+7
    float4 v0; v0.x = a0 * dn; v0.y = a1 * dn; v0.z = a2 * dn; v0.w = a3 * dn;
    float4 v1; v1.x = a4 * dn; v1.y = a5 * dn; v1.z = a6 * dn; v1.w = a7 * dn;
    *(float4*)&sh[w][(l << 3) + 0] = v0;
    *(float4*)&sh[w][(l << 3) + 4] = v1;
  }
  __syncthreads();

  float t = b2[l];
  const float4* shv = (const float4*)sh[w];
#pragma unroll 4
  for (int j4 = 0; j4 < 16; ++j4) {
    float4 a4v = shv[j4];
    t += a4v.x * W2[(4 * j4 + 0) * 64 + l];
    t += a4v.y * W2[(4 * j4 + 1) * 64 + l];
    t += a4v.z * W2[(4 * j4 + 2) * 64 + l];
    t += a4v.w * W2[(4 * j4 + 3) * 64 + l];
  }
  t = fmaxf(t, 0.0f);

  float p0 = t * Wf[l * 2 + 0];
  float p1 = t * Wf[l * 2 + 1];
  for (int off = 32; off; off >>= 1) {
    p0 += __shfl_down(p0, off);
    p1 += __shfl_down(p1, off);
  }
  if (l == 0) {
    out[n * 2 + 0] = p0 + bf[0];
    out[n * 2 + 1] = p1 + bf[1];
  }
}

// ---------------- launch ----------------

extern "C" void kernel_launch(void* const* d_in, const int* in_sizes, int n_in,
                              void* d_out, int out_size, void* d_ws, size_t ws_size,
                              hipStream_t stream) {
  const float* x  = (const float*)d_in[0];
  const int*   ei = (const int*)d_in[1];     // [2, E] row-major, int32
  const float* W1 = (const float*)d_in[2];
  const float* b1 = (const float*)d_in[3];
  const float* W2 = (const float*)d_in[4];
  const float* b2 = (const float*)d_in[5];
  const float* Wf = (const float*)d_in[6];
  const float* bf = (const float*)d_in[7];
  float* out = (float*)d_out;

  const int* srcv = ei;
  const int* dstv = ei + N_EDGES;

  char* p = (char*)d_ws;
  auto take = [&](size_t bytes) { char* r = p; p += (bytes + 255) & ~(size_t)255; return r; };
  int*          gcur = (int*)take((size_t)NBUCKET * 4);
  unsigned int* eb   = (unsigned int*)take((size_t)NBUCKET * BCAP * 4 + 512);  // padded CSR
  int*          rs   = (int*)take((size_t)N_NODES * 4);
  int*          re   = (int*)take((size_t)N_NODES * 4);
  float*        dis  = (float*)take((size_t)N_NODES * 4);
  float4*       xd   = (float4*)take((size_t)(N_NODES + 1) * 16);               // + zero row
  __hip_bfloat16* h1s = (__hip_bfloat16*)take((size_t)(N_NODES + 1) * 64 * 2);  // + zero row

  (void)hipMemsetAsync(gcur, 0, (size_t)NBUCKET * 4, stream);
  k_pass1<<<NPB, 256, 0, stream>>>(srcv, dstv, gcur, eb);
  k_part2<<<NBUCKET, 256, 0, stream>>>(eb, gcur, rs, re, dis, (const float4*)x, xd);
  const int* csr = (const int*)eb;
  k_l1<<<((N_NODES + 1) * 4 + 255) / 256, 256, 0, stream>>>(xd, dis, rs, re, csr, W1, b1, (unsigned int*)h1s);
  k_layer2<<<N_NODES / 4, 256, 0, stream>>>(h1s, dis, rs, re, csr, W2, b2, Wf, bf, out);
}